// Round 3
// baseline (813.478 us; speedup 1.0000x reference)
//
#include <hip/hip_runtime.h>
#include <hip/hip_bf16.h>

#define N_UNIQ 20000
#define K_NBR 32
#define BATCH 40000
// Inputs fp32, output fp32. Internal: F bf16 [N_UNIQ][384] (MFMA A-operand),
// G fp32 [N_UNIQ][384] (final normalized rows), packed bf16 weight frags.

typedef unsigned short ushort_t;
typedef __bf16 bfrag __attribute__((ext_vector_type(8)));   // 8 bf16 = 4 VGPRs (MFMA A/B)
typedef float  ffrag __attribute__((ext_vector_type(4)));   // MFMA C/D

__device__ __forceinline__ ushort_t f2bf(float f) {
    unsigned u = __builtin_bit_cast(unsigned, f);
    unsigned r = u + 0x7fffu + ((u >> 16) & 1u);   // round-to-nearest-even
    return (ushort_t)(r >> 16);
}
__device__ __forceinline__ unsigned pack2(float x, float y) {
    return (unsigned)f2bf(x) | ((unsigned)f2bf(y) << 16);
}

// ---------------------------------------------------------------------------
// Pack fp32 W ([K][N] row-major = reference's [in,out]) into bf16 MFMA
// B-fragment order: frag for lane l, k-step kk, n-tile nt holds
//   B[k = kk*32 + (l>>4)*8 + j][n = nt*16 + (l&15)], j=0..7  (16 B per lane)
// wp1: 3 chunks (self/adj/dis), each K=128 (4 kk) x N=128 (8 nt) -> 6144 frags
// wp2: WC, K=384 (12 kk) x N=384 (24 nt)                        -> 18432 frags
// ---------------------------------------------------------------------------
__global__ void pack_kernel(const float* __restrict__ Ws,
                            const float* __restrict__ Wa,
                            const float* __restrict__ Wd,
                            const float* __restrict__ WC,
                            uint4* __restrict__ wp1, uint4* __restrict__ wp2) {
    int t = blockIdx.x * blockDim.x + threadIdx.x;   // 0 .. 24575
    int l = t & 63, q = l >> 4, m = l & 15;
    ushort_t v[8];
    if (t < 6144) {                 // 3 * 8nt * 4kk * 64
        int g   = t >> 11;
        int rem = t & 2047;
        int nt  = rem >> 8;
        int kk  = (rem >> 6) & 3;
        const float* W = (g == 0) ? Ws : ((g == 1) ? Wa : Wd);
#pragma unroll
        for (int j = 0; j < 8; j++)
            v[j] = f2bf(W[(kk * 32 + q * 8 + j) * 128 + nt * 16 + m]);
        uint4 u; __builtin_memcpy(&u, v, 16);
        wp1[t] = u;
    } else {
        int t2 = t - 6144;          // 24nt * 12kk * 64
        int nt = t2 / 768;
        int kk = (t2 >> 6) % 12;
#pragma unroll
        for (int j = 0; j < 8; j++)
            v[j] = f2bf(WC[(kk * 32 + q * 8 + j) * 384 + nt * 16 + m]);
        uint4 u; __builtin_memcpy(&u, v, 16);
        wp2[t2] = u;
    }
}

// ---------------------------------------------------------------------------
// Aggregation: one wave per unique node. Lane l covers fp32 cols 2l, 2l+1.
// F row (384 bf16): [0:128)=feat[self], [128:256)=mean adj, [256:384)=mean dis
// ---------------------------------------------------------------------------
__global__ void agg_kernel(const int* __restrict__ uniq,
                           const int* __restrict__ adjn,
                           const int* __restrict__ disn,
                           const float* __restrict__ feat,
                           ushort_t* __restrict__ F) {
    int wave = (blockIdx.x * blockDim.x + threadIdx.x) >> 6;
    int l = threadIdx.x & 63;
    if (wave >= N_UNIQ) return;

    int my = (l < 32) ? adjn[wave * K_NBR + l] : disn[wave * K_NBR + (l - 32)];

    float a0 = 0.f, a1 = 0.f, d0 = 0.f, d1 = 0.f;
#pragma unroll 8
    for (int i = 0; i < 32; i++) {
        int ra = __shfl(my, i);
        int rd = __shfl(my, 32 + i);
        float2 fa = *(const float2*)(feat + (size_t)ra * 128 + l * 2);
        float2 fd = *(const float2*)(feat + (size_t)rd * 128 + l * 2);
        a0 += fa.x; a1 += fa.y;
        d0 += fd.x; d1 += fd.y;
    }
    float2 fs = *(const float2*)(feat + (size_t)uniq[wave] * 128 + l * 2);

    const float inv = 1.0f / 32.0f;
    ushort_t* row = F + (size_t)wave * 384;
    *(unsigned*)(row + l * 2)       = pack2(fs.x, fs.y);
    *(unsigned*)(row + 128 + l * 2) = pack2(a0 * inv, a1 * inv);
    *(unsigned*)(row + 256 + l * 2) = pack2(d0 * inv, d1 * inv);
}

// ---------------------------------------------------------------------------
// GEMM1 (in-place on F): Y[r, nt*16:..] = X[r, g*128:..] @ W_g + bias
// Wave per 16-row M-tile; X row slice pre-loaded into 12 uint4 A-frags.
// A-frag: A[m=lane&15][k = kk*32 + (lane>>4)*8 + j]   (verified m89/m91/m120)
// D-frag: col=lane&15, row=(lane>>4)*4 + r
// ---------------------------------------------------------------------------
__global__ void gemm1_kernel(ushort_t* __restrict__ F,
                             const uint4* __restrict__ wp1,
                             const float* __restrict__ bias) {
    int wv = blockIdx.x * 4 + (threadIdx.x >> 6);
    if (wv >= N_UNIQ / 16) return;
    int l = threadIdx.x & 63, q = l >> 4, m = l & 15;
    int m0 = wv * 16;

    uint4 a[12];
    const ushort_t* xrow = F + (size_t)(m0 + m) * 384;
#pragma unroll
    for (int kk = 0; kk < 12; kk++)
        a[kk] = *(const uint4*)(xrow + kk * 32 + q * 8);

    ushort_t outv[24][4];
#pragma unroll
    for (int nt = 0; nt < 24; nt++) {
        int g = nt >> 3;
        ffrag acc = {0.f, 0.f, 0.f, 0.f};
        const uint4* wp = wp1 + (size_t)nt * 4 * 64;
#pragma unroll
        for (int kk = 0; kk < 4; kk++) {
            bfrag bf = __builtin_bit_cast(bfrag, wp[kk * 64 + l]);
            bfrag af = __builtin_bit_cast(bfrag, a[g * 4 + kk]);
            acc = __builtin_amdgcn_mfma_f32_16x16x32_bf16(af, bf, acc, 0, 0, 0);
        }
        float bv = bias[nt * 16 + m];
#pragma unroll
        for (int r = 0; r < 4; r++) outv[nt][r] = f2bf(acc[r] + bv);
    }
    // rows owned exclusively by this wave -> safe in-place store
#pragma unroll
    for (int nt = 0; nt < 24; nt++) {
        int col = nt * 16 + m;
#pragma unroll
        for (int r = 0; r < 4; r++)
            F[(size_t)(m0 + q * 4 + r) * 384 + col] = outv[nt][r];
    }
}

// ---------------------------------------------------------------------------
// GEMM2: G = normalize(leaky(F @ WC + WC_b))   (G fp32, F untouched)
// ---------------------------------------------------------------------------
__global__ void gemm2_kernel(const ushort_t* __restrict__ F,
                             const uint4* __restrict__ wp2,
                             const float* __restrict__ wcb,
                             float* __restrict__ G) {
    int wv = blockIdx.x * 4 + (threadIdx.x >> 6);
    if (wv >= N_UNIQ / 16) return;
    int l = threadIdx.x & 63, q = l >> 4, m = l & 15;
    int m0 = wv * 16;

    uint4 a[12];
    const ushort_t* xrow = F + (size_t)(m0 + m) * 384;
#pragma unroll
    for (int kk = 0; kk < 12; kk++)
        a[kk] = *(const uint4*)(xrow + kk * 32 + q * 8);

    float vals[24][4];
    float ss[4] = {0.f, 0.f, 0.f, 0.f};
#pragma unroll
    for (int nt = 0; nt < 24; nt++) {
        ffrag acc = {0.f, 0.f, 0.f, 0.f};
        const uint4* wp = wp2 + (size_t)nt * 12 * 64;
#pragma unroll
        for (int kk = 0; kk < 12; kk++) {
            bfrag bf = __builtin_bit_cast(bfrag, wp[kk * 64 + l]);
            bfrag af = __builtin_bit_cast(bfrag, a[kk]);
            acc = __builtin_amdgcn_mfma_f32_16x16x32_bf16(af, bf, acc, 0, 0, 0);
        }
        float bv = wcb[nt * 16 + m];
#pragma unroll
        for (int r = 0; r < 4; r++) {
            float v = acc[r] + bv;
            v = (v >= 0.f) ? v : 0.2f * v;      // LeakyReLU(0.2)
            vals[nt][r] = v;
            ss[r] += v * v;
        }
    }
    // row sum-of-squares: reduce across the 16 lanes (cols) of each quad
#pragma unroll
    for (int r = 0; r < 4; r++) {
        float s = ss[r];
        s += __shfl_xor(s, 1);
        s += __shfl_xor(s, 2);
        s += __shfl_xor(s, 4);
        s += __shfl_xor(s, 8);
        float nrm = fmaxf(sqrtf(s), 1e-12f);
        ss[r] = 1.0f / nrm;
    }
#pragma unroll
    for (int nt = 0; nt < 24; nt++) {
        int col = nt * 16 + m;
#pragma unroll
        for (int r = 0; r < 4; r++)
            G[(size_t)(m0 + q * 4 + r) * 384 + col] = vals[nt][r] * ss[r];
    }
}

// ---------------------------------------------------------------------------
// Output gather (fp32): out[b,:] = G[nodes_idx[b],:]  (96 uint4 per row)
// ---------------------------------------------------------------------------
__global__ void gather_kernel(const int* __restrict__ nidx,
                              const uint4* __restrict__ G4,
                              uint4* __restrict__ out4) {
    int t = blockIdx.x * blockDim.x + threadIdx.x;
    if (t >= BATCH * 96) return;
    int b = t / 96, c = t - b * 96;
    int row = nidx[b];
    out4[(size_t)b * 96 + c] = G4[(size_t)row * 96 + c];
}

extern "C" void kernel_launch(void* const* d_in, const int* in_sizes, int n_in,
                              void* d_out, int out_size, void* d_ws, size_t ws_size,
                              hipStream_t stream) {
    const int*   uniq = (const int*)d_in[0];
    const int*   adjn = (const int*)d_in[1];
    const int*   disn = (const int*)d_in[2];
    const int*   nidx = (const int*)d_in[3];
    const float* feat = (const float*)d_in[4];
    const float* Ws   = (const float*)d_in[5];
    const float* Wa   = (const float*)d_in[6];
    const float* Wd   = (const float*)d_in[7];
    const float* bias = (const float*)d_in[8];
    const float* WC   = (const float*)d_in[9];
    const float* wcb  = (const float*)d_in[10];

    ushort_t* F   = (ushort_t*)d_ws;                            // 15,360,000 B (bf16)
    float*    G   = (float*)((char*)d_ws + 15360000);           // 30,720,000 B (fp32)
    uint4*    wp1 = (uint4*)((char*)d_ws + 46080000);           // 98,304 B
    uint4*    wp2 = (uint4*)((char*)d_ws + 46178304);           // 294,912 B

    pack_kernel<<<96, 256, 0, stream>>>(Ws, Wa, Wd, WC, wp1, wp2);
    agg_kernel<<<N_UNIQ / 4, 256, 0, stream>>>(uniq, adjn, disn, feat, F);
    gemm1_kernel<<<(N_UNIQ / 16 + 3) / 4, 256, 0, stream>>>(F, wp1, bias);
    gemm2_kernel<<<(N_UNIQ / 16 + 3) / 4, 256, 0, stream>>>(F, wp2, wcb, G);
    gather_kernel<<<BATCH * 96 / 256, 256, 0, stream>>>(nidx, (const uint4*)G, (uint4*)d_out);
}